// Round 10
// baseline (244.518 us; speedup 1.0000x reference)
//
#include <hip/hip_runtime.h>
#include <hip/hip_bf16.h>

// SplitRoundGIN: N=100000, E=1200000, D=64, RW=3, L=2, eps=-1 (pure neighbor sum).
// R9: zero-global-atomic CSR build. Per-XCD node ranges (12.5k nodes, 50KB LDS):
//   histA: per (xcd, edge-slice) block, LDS histogram of in-range dsts -> u16 Htab
//   hscan: per node, exclusive prefix over the 32 slice counts -> Btab, cnt
//   fillB: reload bases into LDS, allocate slots via LDS atomicAdd, store packed
// Gathers (R8 branchless half-wave) and ln unchanged.
constexpr int NN  = 100000;
constexpr int EE  = 1200000;
constexpr int D   = 64;
constexpr int CAP = 64;                  // max degree bucket (P(deg>64) ~ 1e-28)
constexpr int ZROW = NN;                 // dedicated all-zero row index
constexpr float LN_EPS = 1e-5f;
constexpr int NXCD = 8;
constexpr int NPX  = NN / NXCD;          // 12500 nodes per XCD range
constexpr int G    = 32;                 // edge slices (blocks per XCD group)
constexpr int FB   = NXCD * G;           // 256 fill blocks
constexpr int EPG  = (EE + G - 1) / G;   // 37500 edges per slice
constexpr int FTH  = 512;                // fill block size

// ---- pass A: per-slice LDS histogram of in-range dsts ----
__global__ __launch_bounds__(FTH) void histA_kernel(const int* __restrict__ dst,
                                                    unsigned short* __restrict__ Htab) {
    __shared__ int hist[NPX];
    int b = blockIdx.x, xcd = b & 7, k = b >> 3;
    int lo = xcd * NPX;
    for (int i = threadIdx.x; i < NPX; i += FTH) hist[i] = 0;
    __syncthreads();
    int e0 = k * EPG, e1 = min(e0 + EPG, EE);
    for (int e = e0 + (int)threadIdx.x; e < e1; e += FTH) {
        int d = dst[e] - lo;
        if ((unsigned)d < (unsigned)NPX) atomicAdd(&hist[d], 1);
    }
    __syncthreads();
    unsigned short* hrow = Htab + (size_t)(xcd * G + k) * NPX;
    for (int i = threadIdx.x; i < NPX; i += FTH) hrow[i] = (unsigned short)hist[i];
}

// ---- pass scan: per node, exclusive prefix over G slice counts; writes cnt ----
__global__ void hscan_kernel(const unsigned short* __restrict__ Htab,
                             unsigned short* __restrict__ Btab, int* __restrict__ cnt) {
    int d = blockIdx.x * blockDim.x + threadIdx.x;
    if (d >= NN) return;
    int xcd = d / NPX, dl = d - xcd * NPX;
    int run = 0;
    #pragma unroll 8
    for (int k = 0; k < G; ++k) {
        size_t idx = (size_t)(xcd * G + k) * NPX + dl;
        int c = Htab[idx];
        Btab[idx] = (unsigned short)run;
        run += c;
    }
    cnt[d] = run;
}

// ---- pass B: allocate slots via LDS cursor, store packed src|age ----
__global__ __launch_bounds__(FTH) void fillB_kernel(const int* __restrict__ src,
                                                    const int* __restrict__ dst,
                                                    const int* __restrict__ age,
                                                    const unsigned short* __restrict__ Btab,
                                                    int* __restrict__ packed) {
    __shared__ int cur[NPX];
    int b = blockIdx.x, xcd = b & 7, k = b >> 3;
    int lo = xcd * NPX;
    const unsigned short* brow = Btab + (size_t)(xcd * G + k) * NPX;
    for (int i = threadIdx.x; i < NPX; i += FTH) cur[i] = brow[i];
    __syncthreads();
    int e0 = k * EPG, e1 = min(e0 + EPG, EE);
    for (int e = e0 + (int)threadIdx.x; e < e1; e += FTH) {
        int d = dst[e] - lo;
        if ((unsigned)d < (unsigned)NPX) {
            int slot = atomicAdd(&cur[d], 1);      // LDS atomic
            if (slot < CAP) {
                int s = src[e];
                packed[(size_t)(d + lo) * CAP + slot] = s | (age[s] << 17);
            }
        }
    }
}

__device__ __forceinline__ float2 bf22f2(ushort2 u) {
    float2 r;
    r.x = __uint_as_float((unsigned)u.x << 16);
    r.y = __uint_as_float((unsigned)u.y << 16);
    return r;
}

__device__ __forceinline__ ushort2 f2bf2(float2 v) {
    __hip_bfloat16 a = __float2bfloat16(v.x);
    __hip_bfloat16 b = __float2bfloat16(v.y);
    ushort2 u;
    u.x = *(const unsigned short*)&a;
    u.y = *(const unsigned short*)&b;
    return u;
}

// Full-row LN over 64 cols held as float2 per lane in a 32-lane group.
__device__ __forceinline__ float2 ln_relu_pair(float2 a, bool relu) {
    float s = a.x + a.y;
    #pragma unroll
    for (int m = 1; m < 32; m <<= 1) s += __shfl_xor(s, m);
    float mu = s * (1.f / 64.f);
    float dx = a.x - mu, dy = a.y - mu;
    float q = dx * dx + dy * dy;
    #pragma unroll
    for (int m = 1; m < 32; m <<= 1) q += __shfl_xor(q, m);
    float rs = rsqrtf(q * (1.f / 64.f) + LN_EPS);
    float2 r;
    r.x = dx * rs;
    r.y = dy * rs;
    if (relu) { r.x = fmaxf(r.x, 0.f); r.y = fmaxf(r.y, 0.f); }
    return r;
}

// hn = LN(feature) -> bf16 plane; zeroes the ZROW rows of hnbf/A1bf.
__global__ void ln_kernel(const float* __restrict__ x, __hip_bfloat16* __restrict__ ybf,
                          __hip_bfloat16* __restrict__ A1bf, int nrows) {
    int gid  = blockIdx.x * blockDim.x + threadIdx.x;
    if (gid < 192) {
        A1bf[(size_t)ZROW * 192 + gid] = __float2bfloat16(0.f);
        if (gid < 64) ybf[(size_t)ZROW * D + gid] = __float2bfloat16(0.f);
    }
    int row  = gid >> 6;
    int lane = gid & 63;
    if (row >= nrows) return;
    size_t i = (size_t)row * D + lane;
    float v = x[i];
    float s = v;
    #pragma unroll
    for (int m = 1; m < 64; m <<= 1) s += __shfl_xor(s, m);
    float mu = s * (1.f / 64.f);
    float d = v - mu;
    float q = d * d;
    #pragma unroll
    for (int m = 1; m < 64; m <<= 1) q += __shfl_xor(q, m);
    float r = d * rsqrtf(q * (1.f / 64.f) + LN_EPS);
    ybf[i] = __float2bfloat16(r);
}

// layer-1 gather (3 windows via age mask) + LN/ReLU + h1 output writes.
// A1bf layout: [node][3][64] bf16 (384B/node). Half-wave edge pairing;
// branchless 16-edge main block, tail loop for deg>16.
__global__ void gather1_kernel(const __hip_bfloat16* __restrict__ hnbf,
                               const int* __restrict__ cnt,
                               const int* __restrict__ packed,
                               __hip_bfloat16* __restrict__ A1bf,
                               float* __restrict__ out) {
    int gid  = blockIdx.x * blockDim.x + threadIdx.x;
    int node = gid >> 6;
    int lane = gid & 63;
    if (node >= NN) return;
    int sl = lane & 31;
    int h  = lane >> 5;
    int n  = min(cnt[node], CAP);
    int nc4 = (n + 3) >> 2;
    int mc  = max(nc4 - 1, 0);
    const int* pl = packed + (size_t)node * CAP;   // 256B-aligned
    float2 a0 = {0.f, 0.f}, a1 = {0.f, 0.f}, a2 = {0.f, 0.f};

    {
        int c0 = min(h, mc), c1 = min(h + 2, mc);
        int4 pa = *reinterpret_cast<const int4*>(pl + 4 * c0);
        int4 pb = *reinterpret_cast<const int4*>(pl + 4 * c1);
        int pA[4] = {pa.x, pa.y, pa.z, pa.w};
        int pB[4] = {pb.x, pb.y, pb.z, pb.w};
        #pragma unroll
        for (int k = 0; k < 8; ++k) {
            int i  = (k < 4) ? (4 * h + k) : (4 * (h + 2) + (k - 4));
            int pk = (k < 4) ? pA[k] : pB[k - 4];
            int idx = (i < n) ? (pk & 0x1FFFF) : ZROW;
            const ushort2* row = reinterpret_cast<const ushort2*>(
                hnbf + (size_t)idx * D);
            float2 v = bf22f2(row[sl]);
            int g = pk >> 17;
            a0.x += v.x; a0.y += v.y;
            if (g >= 1) { a1.x += v.x; a1.y += v.y; }
            if (g >= 2) { a2.x += v.x; a2.y += v.y; }
        }
    }
    for (int c = 4 + h; c < nc4; c += 2) {
        int4 pc = *reinterpret_cast<const int4*>(pl + 4 * c);
        int pC[4] = {pc.x, pc.y, pc.z, pc.w};
        #pragma unroll
        for (int k = 0; k < 4; ++k) {
            int i = 4 * c + k;
            int idx = (i < n) ? (pC[k] & 0x1FFFF) : ZROW;
            const ushort2* row = reinterpret_cast<const ushort2*>(
                hnbf + (size_t)idx * D);
            float2 v = bf22f2(row[sl]);
            int g = pC[k] >> 17;
            a0.x += v.x; a0.y += v.y;
            if (g >= 1) { a1.x += v.x; a1.y += v.y; }
            if (g >= 2) { a2.x += v.x; a2.y += v.y; }
        }
    }
    a0.x += __shfl_xor(a0.x, 32); a0.y += __shfl_xor(a0.y, 32);
    a1.x += __shfl_xor(a1.x, 32); a1.y += __shfl_xor(a1.y, 32);
    a2.x += __shfl_xor(a2.x, 32); a2.y += __shfl_xor(a2.y, 32);

    float2 r0 = ln_relu_pair(a0, true);
    float2 r1 = ln_relu_pair(a1, true);
    float2 r2 = ln_relu_pair(a2, true);

    ushort2* rw = reinterpret_cast<ushort2*>(A1bf + (size_t)node * (3 * D));
    float* ob = out + (size_t)node * 384;
    if (h == 0) {
        rw[sl] = f2bf2(r0);                                    // w0
        reinterpret_cast<float2*>(ob + 64)[sl] = r0;           // out slot 1
    } else {
        rw[32 + sl] = f2bf2(r1);                               // w1
        rw[64 + sl] = f2bf2(r2);                               // w2
        float2 o4;
        o4.x = r0.x - 0.5f * (r1.x + r2.x);
        o4.y = r0.y - 0.5f * (r1.y + r2.y);
        reinterpret_cast<float2*>(ob + 256)[sl] = o4;          // out slot 4
    }
}

// layer-2 gather + LN/ReLU + remaining output slots.
__global__ void gather2_kernel(const __hip_bfloat16* __restrict__ hnbf,
                               const __hip_bfloat16* __restrict__ A1bf,
                               const int* __restrict__ cnt, const int* __restrict__ packed,
                               const int* __restrict__ age, float* __restrict__ out) {
    int gid  = blockIdx.x * blockDim.x + threadIdx.x;
    int node = gid >> 6;
    int lane = gid & 63;
    if (node >= NN) return;
    int sl = lane & 31;
    int h  = lane >> 5;
    int n  = min(cnt[node], CAP);
    int nc4 = (n + 3) >> 2;
    int mc  = max(nc4 - 1, 0);
    const int* pl = packed + (size_t)node * CAP;
    float2 a0 = {0.f, 0.f}, a1 = {0.f, 0.f}, a2 = {0.f, 0.f};

    {
        int c0 = min(h, mc), c1 = min(h + 2, mc);
        int4 pa = *reinterpret_cast<const int4*>(pl + 4 * c0);
        int4 pb = *reinterpret_cast<const int4*>(pl + 4 * c1);
        int pA[4] = {pa.x, pa.y, pa.z, pa.w};
        int pB[4] = {pb.x, pb.y, pb.z, pb.w};
        #pragma unroll
        for (int k = 0; k < 8; ++k) {
            int i  = (k < 4) ? (4 * h + k) : (4 * (h + 2) + (k - 4));
            int pk = (k < 4) ? pA[k] : pB[k - 4];
            int idx = (i < n) ? (pk & 0x1FFFF) : ZROW;
            const ushort2* row = reinterpret_cast<const ushort2*>(
                A1bf + (size_t)idx * (3 * D));
            float2 v0 = bf22f2(row[sl]);        // w0
            float2 v1 = bf22f2(row[32 + sl]);   // w1 (+128B)
            float2 v2 = bf22f2(row[64 + sl]);   // w2 (+256B)
            a0.x += v0.x; a0.y += v0.y;
            a1.x += v1.x; a1.y += v1.y;
            a2.x += v2.x; a2.y += v2.y;
        }
    }
    for (int c = 4 + h; c < nc4; c += 2) {
        int4 pc = *reinterpret_cast<const int4*>(pl + 4 * c);
        int pC[4] = {pc.x, pc.y, pc.z, pc.w};
        #pragma unroll
        for (int k = 0; k < 4; ++k) {
            int i = 4 * c + k;
            int idx = (i < n) ? (pC[k] & 0x1FFFF) : ZROW;
            const ushort2* row = reinterpret_cast<const ushort2*>(
                A1bf + (size_t)idx * (3 * D));
            float2 v0 = bf22f2(row[sl]);
            float2 v1 = bf22f2(row[32 + sl]);
            float2 v2 = bf22f2(row[64 + sl]);
            a0.x += v0.x; a0.y += v0.y;
            a1.x += v1.x; a1.y += v1.y;
            a2.x += v2.x; a2.y += v2.y;
        }
    }
    a0.x += __shfl_xor(a0.x, 32); a0.y += __shfl_xor(a0.y, 32);
    a1.x += __shfl_xor(a1.x, 32); a1.y += __shfl_xor(a1.y, 32);
    a2.x += __shfl_xor(a2.x, 32); a2.y += __shfl_xor(a2.y, 32);

    float2 h20 = ln_relu_pair(a0, true);
    float2 h21 = ln_relu_pair(a1, true);
    float2 h22 = ln_relu_pair(a2, true);

    float2 hnv = bf22f2(reinterpret_cast<const ushort2*>(
        hnbf + (size_t)node * D)[sl]);
    int ag = age[node];
    float f = 1.f - 0.5f * (float)((ag >= 1) + (ag >= 2));
    float* ob = out + (size_t)node * 384;
    if (h == 0) {
        reinterpret_cast<float2*>(ob)[sl] = hnv;               // slot 0
        reinterpret_cast<float2*>(ob + 128)[sl] = h20;         // slot 2
    } else {
        float2 o3, o5;
        o3.x = hnv.x * f;
        o3.y = hnv.y * f;
        o5.x = h20.x - 0.5f * (h21.x + h22.x);
        o5.y = h20.y - 0.5f * (h21.y + h22.y);
        reinterpret_cast<float2*>(ob + 192)[sl] = o3;          // slot 3
        reinterpret_cast<float2*>(ob + 320)[sl] = o5;          // slot 5
    }
}

extern "C" void kernel_launch(void* const* d_in, const int* in_sizes, int n_in,
                              void* d_out, int out_size, void* d_ws, size_t ws_size,
                              hipStream_t stream) {
    const float* feature = (const float*)d_in[0];
    const int*   age     = (const int*)d_in[1];
    const int*   src     = (const int*)d_in[2];
    const int*   dst     = (const int*)d_in[3];
    float* out = (float*)d_out;

    size_t nd1 = (size_t)(NN + 1) * D;               // hnbf rows incl. zero row
    __hip_bfloat16* hnbf = (__hip_bfloat16*)d_ws;    // [NN+1][D]      ~12.8 MB
    __hip_bfloat16* A1bf = hnbf + nd1;               // [NN+1][3][D]   ~38.4 MB
    int* cnt    = (int*)(A1bf + (size_t)(NN + 1) * 3 * D);   // NN      0.4 MB
    int* packed = cnt + NN;                          // NN*CAP          25.6 MB
    unsigned short* Htab = (unsigned short*)(packed + (size_t)NN * CAP); // 8*G*NPX  6.4 MB
    unsigned short* Btab = Htab + (size_t)NXCD * G * NPX;                // 6.4 MB

    ln_kernel<<<(int)(((size_t)NN * D + 255) / 256), 256, 0, stream>>>(
        feature, hnbf, A1bf, NN);
    histA_kernel<<<FB, FTH, 0, stream>>>(dst, Htab);
    hscan_kernel<<<(NN + 255) / 256, 256, 0, stream>>>(Htab, Btab, cnt);
    fillB_kernel<<<FB, FTH, 0, stream>>>(src, dst, age, Btab, packed);
    gather1_kernel<<<(NN * 64 + 255) / 256, 256, 0, stream>>>(hnbf, cnt, packed, A1bf, out);
    gather2_kernel<<<(NN * 64 + 255) / 256, 256, 0, stream>>>(hnbf, A1bf, cnt, packed,
                                                              age, out);
}

// Round 13
// 217.317 us; speedup vs baseline: 1.1252x; 1.1252x over previous
//
#include <hip/hip_runtime.h>
#include <hip/hip_bf16.h>

// SplitRoundGIN: N=100000, E=1200000, D=64, RW=3, L=2, eps=-1 (pure neighbor sum).
// R12 = R8 (best passing: 207.6us) + CAP 64->48 (packed 19.2MB, better L2 fit)
//     + fillx reads dst as nontemporal int4 (ext_vector_type -- HIP int4 class
//       is rejected by __builtin_nontemporal_load), 4 edges/thread-iter.
// R9's LDS-histogram build REGRESSED (244us) -> global-atomic fillx retained.
constexpr int NN  = 100000;
constexpr int EE  = 1200000;
constexpr int D   = 64;
constexpr int CAP = 48;                  // max degree bucket (max deg ~33; P(deg>48)~4e-10)
constexpr int ZROW = NN;                 // dedicated all-zero row index
constexpr float LN_EPS = 1e-5f;
constexpr int NXCD = 8;
constexpr int NPX  = (NN + NXCD - 1) / NXCD;     // 12500 nodes per XCD range
constexpr int FILL_GRP = 256;                    // blocks per XCD group
constexpr int FILL_BLOCKS = NXCD * FILL_GRP;     // 2048
constexpr int FEPG = ((EE + FILL_GRP - 1) / FILL_GRP + 3) & ~3;  // 4688 (div 4)

typedef int int4v __attribute__((ext_vector_type(4)));

__global__ void fillx_kernel(const int* __restrict__ src, const int* __restrict__ dst,
                             const int* __restrict__ age, int* __restrict__ cnt,
                             int* __restrict__ packed) {
    int bid = blockIdx.x;
    int xcd = bid & 7;                   // -> XCD via round-robin dispatch
    int grp = bid >> 3;                  // 0..FILL_GRP-1
    int lo = xcd * NPX;
    int hi = min(lo + NPX, NN);
    int e0 = grp * FEPG;
    int e1 = min(e0 + FEPG, EE);
    for (int e = e0 + 4 * (int)threadIdx.x; e < e1; e += 4 * (int)blockDim.x) {
        int4v dv = __builtin_nontemporal_load(reinterpret_cast<const int4v*>(dst + e));
        #pragma unroll
        for (int k = 0; k < 4; ++k) {
            int d = dv[k];
            if (d >= lo && d < hi) {
                int slot = atomicAdd(&cnt[d], 1);
                if (slot < CAP) {
                    int s = src[e + k];
                    packed[(size_t)d * CAP + slot] = s | (age[s] << 17);
                }
            }
        }
    }
}

__device__ __forceinline__ float2 bf22f2(ushort2 u) {
    float2 r;
    r.x = __uint_as_float((unsigned)u.x << 16);
    r.y = __uint_as_float((unsigned)u.y << 16);
    return r;
}

__device__ __forceinline__ ushort2 f2bf2(float2 v) {
    __hip_bfloat16 a = __float2bfloat16(v.x);
    __hip_bfloat16 b = __float2bfloat16(v.y);
    ushort2 u;
    u.x = *(const unsigned short*)&a;
    u.y = *(const unsigned short*)&b;
    return u;
}

// Full-row LN over 64 cols held as float2 per lane in a 32-lane group.
__device__ __forceinline__ float2 ln_relu_pair(float2 a, bool relu) {
    float s = a.x + a.y;
    #pragma unroll
    for (int m = 1; m < 32; m <<= 1) s += __shfl_xor(s, m);
    float mu = s * (1.f / 64.f);
    float dx = a.x - mu, dy = a.y - mu;
    float q = dx * dx + dy * dy;
    #pragma unroll
    for (int m = 1; m < 32; m <<= 1) q += __shfl_xor(q, m);
    float rs = rsqrtf(q * (1.f / 64.f) + LN_EPS);
    float2 r;
    r.x = dx * rs;
    r.y = dy * rs;
    if (relu) { r.x = fmaxf(r.x, 0.f); r.y = fmaxf(r.y, 0.f); }
    return r;
}

// hn = LN(feature) -> bf16 plane; zeroes cnt and the ZROW rows of hnbf/A1bf.
__global__ void ln_kernel(const float* __restrict__ x, __hip_bfloat16* __restrict__ ybf,
                          __hip_bfloat16* __restrict__ A1bf, int* __restrict__ cnt,
                          int nrows) {
    int gid  = blockIdx.x * blockDim.x + threadIdx.x;
    if (gid < NN) cnt[gid] = 0;
    if (gid < 192) {
        A1bf[(size_t)ZROW * 192 + gid] = __float2bfloat16(0.f);
        if (gid < 64) ybf[(size_t)ZROW * D + gid] = __float2bfloat16(0.f);
    }
    int row  = gid >> 6;
    int lane = gid & 63;
    if (row >= nrows) return;
    size_t i = (size_t)row * D + lane;
    float v = x[i];
    float s = v;
    #pragma unroll
    for (int m = 1; m < 64; m <<= 1) s += __shfl_xor(s, m);
    float mu = s * (1.f / 64.f);
    float d = v - mu;
    float q = d * d;
    #pragma unroll
    for (int m = 1; m < 64; m <<= 1) q += __shfl_xor(q, m);
    float r = d * rsqrtf(q * (1.f / 64.f) + LN_EPS);
    ybf[i] = __float2bfloat16(r);
}

// layer-1 gather (3 windows via age mask) + LN/ReLU + h1 output writes.
// A1bf layout: [node][3][64] bf16 (384B/node). Half-wave edge pairing;
// branchless 16-edge main block, tail loop for deg>16.
__global__ void gather1_kernel(const __hip_bfloat16* __restrict__ hnbf,
                               const int* __restrict__ cnt,
                               const int* __restrict__ packed,
                               __hip_bfloat16* __restrict__ A1bf,
                               float* __restrict__ out) {
    int gid  = blockIdx.x * blockDim.x + threadIdx.x;
    int node = gid >> 6;
    int lane = gid & 63;
    if (node >= NN) return;
    int sl = lane & 31;
    int h  = lane >> 5;
    int n  = min(cnt[node], CAP);
    int nc4 = (n + 3) >> 2;
    int mc  = max(nc4 - 1, 0);
    const int* pl = packed + (size_t)node * CAP;   // 192B rows, 16B-aligned
    float2 a0 = {0.f, 0.f}, a1 = {0.f, 0.f}, a2 = {0.f, 0.f};

    {
        int c0 = min(h, mc), c1 = min(h + 2, mc);
        int4 pa = *reinterpret_cast<const int4*>(pl + 4 * c0);
        int4 pb = *reinterpret_cast<const int4*>(pl + 4 * c1);
        int pA[4] = {pa.x, pa.y, pa.z, pa.w};
        int pB[4] = {pb.x, pb.y, pb.z, pb.w};
        #pragma unroll
        for (int k = 0; k < 8; ++k) {
            int i  = (k < 4) ? (4 * h + k) : (4 * (h + 2) + (k - 4));
            int pk = (k < 4) ? pA[k] : pB[k - 4];
            int idx = (i < n) ? (pk & 0x1FFFF) : ZROW;
            const ushort2* row = reinterpret_cast<const ushort2*>(
                hnbf + (size_t)idx * D);
            float2 v = bf22f2(row[sl]);
            int g = pk >> 17;
            a0.x += v.x; a0.y += v.y;
            if (g >= 1) { a1.x += v.x; a1.y += v.y; }
            if (g >= 2) { a2.x += v.x; a2.y += v.y; }
        }
    }
    for (int c = 4 + h; c < nc4; c += 2) {
        int4 pc = *reinterpret_cast<const int4*>(pl + 4 * c);
        int pC[4] = {pc.x, pc.y, pc.z, pc.w};
        #pragma unroll
        for (int k = 0; k < 4; ++k) {
            int i = 4 * c + k;
            int idx = (i < n) ? (pC[k] & 0x1FFFF) : ZROW;
            const ushort2* row = reinterpret_cast<const ushort2*>(
                hnbf + (size_t)idx * D);
            float2 v = bf22f2(row[sl]);
            int g = pC[k] >> 17;
            a0.x += v.x; a0.y += v.y;
            if (g >= 1) { a1.x += v.x; a1.y += v.y; }
            if (g >= 2) { a2.x += v.x; a2.y += v.y; }
        }
    }
    a0.x += __shfl_xor(a0.x, 32); a0.y += __shfl_xor(a0.y, 32);
    a1.x += __shfl_xor(a1.x, 32); a1.y += __shfl_xor(a1.y, 32);
    a2.x += __shfl_xor(a2.x, 32); a2.y += __shfl_xor(a2.y, 32);

    float2 r0 = ln_relu_pair(a0, true);
    float2 r1 = ln_relu_pair(a1, true);
    float2 r2 = ln_relu_pair(a2, true);

    ushort2* rw = reinterpret_cast<ushort2*>(A1bf + (size_t)node * (3 * D));
    float* ob = out + (size_t)node * 384;
    if (h == 0) {
        rw[sl] = f2bf2(r0);                                    // w0
        reinterpret_cast<float2*>(ob + 64)[sl] = r0;           // out slot 1
    } else {
        rw[32 + sl] = f2bf2(r1);                               // w1
        rw[64 + sl] = f2bf2(r2);                               // w2
        float2 o4;
        o4.x = r0.x - 0.5f * (r1.x + r2.x);
        o4.y = r0.y - 0.5f * (r1.y + r2.y);
        reinterpret_cast<float2*>(ob + 256)[sl] = o4;          // out slot 4
    }
}

// layer-2 gather + LN/ReLU + remaining output slots.
__global__ void gather2_kernel(const __hip_bfloat16* __restrict__ hnbf,
                               const __hip_bfloat16* __restrict__ A1bf,
                               const int* __restrict__ cnt, const int* __restrict__ packed,
                               const int* __restrict__ age, float* __restrict__ out) {
    int gid  = blockIdx.x * blockDim.x + threadIdx.x;
    int node = gid >> 6;
    int lane = gid & 63;
    if (node >= NN) return;
    int sl = lane & 31;
    int h  = lane >> 5;
    int n  = min(cnt[node], CAP);
    int nc4 = (n + 3) >> 2;
    int mc  = max(nc4 - 1, 0);
    const int* pl = packed + (size_t)node * CAP;
    float2 a0 = {0.f, 0.f}, a1 = {0.f, 0.f}, a2 = {0.f, 0.f};

    {
        int c0 = min(h, mc), c1 = min(h + 2, mc);
        int4 pa = *reinterpret_cast<const int4*>(pl + 4 * c0);
        int4 pb = *reinterpret_cast<const int4*>(pl + 4 * c1);
        int pA[4] = {pa.x, pa.y, pa.z, pa.w};
        int pB[4] = {pb.x, pb.y, pb.z, pb.w};
        #pragma unroll
        for (int k = 0; k < 8; ++k) {
            int i  = (k < 4) ? (4 * h + k) : (4 * (h + 2) + (k - 4));
            int pk = (k < 4) ? pA[k] : pB[k - 4];
            int idx = (i < n) ? (pk & 0x1FFFF) : ZROW;
            const ushort2* row = reinterpret_cast<const ushort2*>(
                A1bf + (size_t)idx * (3 * D));
            float2 v0 = bf22f2(row[sl]);        // w0
            float2 v1 = bf22f2(row[32 + sl]);   // w1 (+128B)
            float2 v2 = bf22f2(row[64 + sl]);   // w2 (+256B)
            a0.x += v0.x; a0.y += v0.y;
            a1.x += v1.x; a1.y += v1.y;
            a2.x += v2.x; a2.y += v2.y;
        }
    }
    for (int c = 4 + h; c < nc4; c += 2) {
        int4 pc = *reinterpret_cast<const int4*>(pl + 4 * c);
        int pC[4] = {pc.x, pc.y, pc.z, pc.w};
        #pragma unroll
        for (int k = 0; k < 4; ++k) {
            int i = 4 * c + k;
            int idx = (i < n) ? (pC[k] & 0x1FFFF) : ZROW;
            const ushort2* row = reinterpret_cast<const ushort2*>(
                A1bf + (size_t)idx * (3 * D));
            float2 v0 = bf22f2(row[sl]);
            float2 v1 = bf22f2(row[32 + sl]);
            float2 v2 = bf22f2(row[64 + sl]);
            a0.x += v0.x; a0.y += v0.y;
            a1.x += v1.x; a1.y += v1.y;
            a2.x += v2.x; a2.y += v2.y;
        }
    }
    a0.x += __shfl_xor(a0.x, 32); a0.y += __shfl_xor(a0.y, 32);
    a1.x += __shfl_xor(a1.x, 32); a1.y += __shfl_xor(a1.y, 32);
    a2.x += __shfl_xor(a2.x, 32); a2.y += __shfl_xor(a2.y, 32);

    float2 h20 = ln_relu_pair(a0, true);
    float2 h21 = ln_relu_pair(a1, true);
    float2 h22 = ln_relu_pair(a2, true);

    float2 hnv = bf22f2(reinterpret_cast<const ushort2*>(
        hnbf + (size_t)node * D)[sl]);
    int ag = age[node];
    float f = 1.f - 0.5f * (float)((ag >= 1) + (ag >= 2));
    float* ob = out + (size_t)node * 384;
    if (h == 0) {
        reinterpret_cast<float2*>(ob)[sl] = hnv;               // slot 0
        reinterpret_cast<float2*>(ob + 128)[sl] = h20;         // slot 2
    } else {
        float2 o3, o5;
        o3.x = hnv.x * f;
        o3.y = hnv.y * f;
        o5.x = h20.x - 0.5f * (h21.x + h22.x);
        o5.y = h20.y - 0.5f * (h21.y + h22.y);
        reinterpret_cast<float2*>(ob + 192)[sl] = o3;          // slot 3
        reinterpret_cast<float2*>(ob + 320)[sl] = o5;          // slot 5
    }
}

extern "C" void kernel_launch(void* const* d_in, const int* in_sizes, int n_in,
                              void* d_out, int out_size, void* d_ws, size_t ws_size,
                              hipStream_t stream) {
    const float* feature = (const float*)d_in[0];
    const int*   age     = (const int*)d_in[1];
    const int*   src     = (const int*)d_in[2];
    const int*   dst     = (const int*)d_in[3];
    float* out = (float*)d_out;

    size_t nd1 = (size_t)(NN + 1) * D;               // hnbf rows incl. zero row
    __hip_bfloat16* hnbf = (__hip_bfloat16*)d_ws;    // [NN+1][D]      ~12.8 MB
    __hip_bfloat16* A1bf = hnbf + nd1;               // [NN+1][3][D]   ~38.4 MB
    int* cnt    = (int*)(A1bf + (size_t)(NN + 1) * 3 * D);   // NN      0.4 MB
    int* packed = cnt + NN;                          // NN*CAP          19.2 MB

    // ln also zeroes cnt and the ZROW rows; must precede fillx/gathers.
    ln_kernel<<<(int)(((size_t)NN * D + 255) / 256), 256, 0, stream>>>(
        feature, hnbf, A1bf, cnt, NN);
    fillx_kernel<<<FILL_BLOCKS, 256, 0, stream>>>(src, dst, age, cnt, packed);
    gather1_kernel<<<(NN * 64 + 255) / 256, 256, 0, stream>>>(hnbf, cnt, packed, A1bf, out);
    gather2_kernel<<<(NN * 64 + 255) / 256, 256, 0, stream>>>(hnbf, A1bf, cnt, packed,
                                                              age, out);
}

// Round 14
// 205.590 us; speedup vs baseline: 1.1893x; 1.0570x over previous
//
#include <hip/hip_runtime.h>
#include <hip/hip_bf16.h>

// SplitRoundGIN: N=100000, E=1200000, D=64, RW=3, L=2, eps=-1 (pure neighbor sum).
// R13 = exact R8 (best: 207.6us; CAP=64, plain scalar fill scan — R12's CAP48/NT
// both regressed) + agePacked: 2-bit ages in a 25KB bitfield (L1-resident) so
// fillx's per-edge age gather is an L1 hit instead of a 400KB L2 gather.
constexpr int NN  = 100000;
constexpr int EE  = 1200000;
constexpr int D   = 64;
constexpr int CAP = 64;                  // max degree bucket (P(deg>64) ~ 1e-28)
constexpr int ZROW = NN;                 // dedicated all-zero row index
constexpr float LN_EPS = 1e-5f;
constexpr int NXCD = 8;
constexpr int NPX  = (NN + NXCD - 1) / NXCD;     // 12500 nodes per XCD range
constexpr int FILL_GRP = 256;                    // blocks per XCD group
constexpr int FILL_BLOCKS = NXCD * FILL_GRP;     // 2048
constexpr int NAPW = (NN + 15) / 16;             // 6250 agePacked words

__global__ void fillx_kernel(const int* __restrict__ src, const int* __restrict__ dst,
                             const unsigned* __restrict__ agePk, int* __restrict__ cnt,
                             int* __restrict__ packed) {
    int bid = blockIdx.x;
    int xcd = bid & 7;                   // -> XCD via round-robin dispatch
    int grp = bid >> 3;                  // 0..FILL_GRP-1
    int lo = xcd * NPX;
    int hi = min(lo + NPX, NN);
    int per = (EE + FILL_GRP - 1) / FILL_GRP;
    int e0 = grp * per;
    int e1 = min(e0 + per, EE);
    for (int e = e0 + (int)threadIdx.x; e < e1; e += (int)blockDim.x) {
        int d = dst[e];
        if (d >= lo && d < hi) {
            int slot = atomicAdd(&cnt[d], 1);
            if (slot < CAP) {
                int s = src[e];
                unsigned aw = agePk[s >> 4];             // 25KB table: L1 hit
                int ag = (aw >> ((s & 15) * 2)) & 3;
                packed[(size_t)d * CAP + slot] = s | (ag << 17);
            }
        }
    }
}

__device__ __forceinline__ float2 bf22f2(ushort2 u) {
    float2 r;
    r.x = __uint_as_float((unsigned)u.x << 16);
    r.y = __uint_as_float((unsigned)u.y << 16);
    return r;
}

__device__ __forceinline__ ushort2 f2bf2(float2 v) {
    __hip_bfloat16 a = __float2bfloat16(v.x);
    __hip_bfloat16 b = __float2bfloat16(v.y);
    ushort2 u;
    u.x = *(const unsigned short*)&a;
    u.y = *(const unsigned short*)&b;
    return u;
}

// Full-row LN over 64 cols held as float2 per lane in a 32-lane group.
__device__ __forceinline__ float2 ln_relu_pair(float2 a, bool relu) {
    float s = a.x + a.y;
    #pragma unroll
    for (int m = 1; m < 32; m <<= 1) s += __shfl_xor(s, m);
    float mu = s * (1.f / 64.f);
    float dx = a.x - mu, dy = a.y - mu;
    float q = dx * dx + dy * dy;
    #pragma unroll
    for (int m = 1; m < 32; m <<= 1) q += __shfl_xor(q, m);
    float rs = rsqrtf(q * (1.f / 64.f) + LN_EPS);
    float2 r;
    r.x = dx * rs;
    r.y = dy * rs;
    if (relu) { r.x = fmaxf(r.x, 0.f); r.y = fmaxf(r.y, 0.f); }
    return r;
}

// hn = LN(feature) -> bf16 plane; zeroes cnt + ZROW rows; builds agePacked.
__global__ void ln_kernel(const float* __restrict__ x, const int* __restrict__ age,
                          __hip_bfloat16* __restrict__ ybf,
                          __hip_bfloat16* __restrict__ A1bf, int* __restrict__ cnt,
                          unsigned* __restrict__ agePk, int nrows) {
    int gid  = blockIdx.x * blockDim.x + threadIdx.x;
    if (gid < NN) cnt[gid] = 0;
    if (gid < 192) {
        A1bf[(size_t)ZROW * 192 + gid] = __float2bfloat16(0.f);
        if (gid < 64) ybf[(size_t)ZROW * D + gid] = __float2bfloat16(0.f);
    }
    if (gid < NAPW) {
        unsigned w = 0;
        int base = gid * 16;
        #pragma unroll
        for (int k = 0; k < 16; ++k) {
            int idx = base + k;
            unsigned a = (idx < NN) ? (unsigned)age[idx] : 0u;
            w |= (a & 3u) << (2 * k);
        }
        agePk[gid] = w;
    }
    int row  = gid >> 6;
    int lane = gid & 63;
    if (row >= nrows) return;
    size_t i = (size_t)row * D + lane;
    float v = x[i];
    float s = v;
    #pragma unroll
    for (int m = 1; m < 64; m <<= 1) s += __shfl_xor(s, m);
    float mu = s * (1.f / 64.f);
    float d = v - mu;
    float q = d * d;
    #pragma unroll
    for (int m = 1; m < 64; m <<= 1) q += __shfl_xor(q, m);
    float r = d * rsqrtf(q * (1.f / 64.f) + LN_EPS);
    ybf[i] = __float2bfloat16(r);
}

// layer-1 gather (3 windows via age mask) + LN/ReLU + h1 output writes.
// A1bf layout: [node][3][64] bf16 (384B/node). Half-wave edge pairing;
// branchless 16-edge main block, tail loop for deg>16.
__global__ void gather1_kernel(const __hip_bfloat16* __restrict__ hnbf,
                               const int* __restrict__ cnt,
                               const int* __restrict__ packed,
                               __hip_bfloat16* __restrict__ A1bf,
                               float* __restrict__ out) {
    int gid  = blockIdx.x * blockDim.x + threadIdx.x;
    int node = gid >> 6;
    int lane = gid & 63;
    if (node >= NN) return;
    int sl = lane & 31;
    int h  = lane >> 5;
    int n  = min(cnt[node], CAP);
    int nc4 = (n + 3) >> 2;
    int mc  = max(nc4 - 1, 0);
    const int* pl = packed + (size_t)node * CAP;   // 256B-aligned
    float2 a0 = {0.f, 0.f}, a1 = {0.f, 0.f}, a2 = {0.f, 0.f};

    {
        int c0 = min(h, mc), c1 = min(h + 2, mc);
        int4 pa = *reinterpret_cast<const int4*>(pl + 4 * c0);
        int4 pb = *reinterpret_cast<const int4*>(pl + 4 * c1);
        int pA[4] = {pa.x, pa.y, pa.z, pa.w};
        int pB[4] = {pb.x, pb.y, pb.z, pb.w};
        #pragma unroll
        for (int k = 0; k < 8; ++k) {
            int i  = (k < 4) ? (4 * h + k) : (4 * (h + 2) + (k - 4));
            int pk = (k < 4) ? pA[k] : pB[k - 4];
            int idx = (i < n) ? (pk & 0x1FFFF) : ZROW;
            const ushort2* row = reinterpret_cast<const ushort2*>(
                hnbf + (size_t)idx * D);
            float2 v = bf22f2(row[sl]);
            int g = pk >> 17;
            a0.x += v.x; a0.y += v.y;
            if (g >= 1) { a1.x += v.x; a1.y += v.y; }
            if (g >= 2) { a2.x += v.x; a2.y += v.y; }
        }
    }
    for (int c = 4 + h; c < nc4; c += 2) {
        int4 pc = *reinterpret_cast<const int4*>(pl + 4 * c);
        int pC[4] = {pc.x, pc.y, pc.z, pc.w};
        #pragma unroll
        for (int k = 0; k < 4; ++k) {
            int i = 4 * c + k;
            int idx = (i < n) ? (pC[k] & 0x1FFFF) : ZROW;
            const ushort2* row = reinterpret_cast<const ushort2*>(
                hnbf + (size_t)idx * D);
            float2 v = bf22f2(row[sl]);
            int g = pC[k] >> 17;
            a0.x += v.x; a0.y += v.y;
            if (g >= 1) { a1.x += v.x; a1.y += v.y; }
            if (g >= 2) { a2.x += v.x; a2.y += v.y; }
        }
    }
    a0.x += __shfl_xor(a0.x, 32); a0.y += __shfl_xor(a0.y, 32);
    a1.x += __shfl_xor(a1.x, 32); a1.y += __shfl_xor(a1.y, 32);
    a2.x += __shfl_xor(a2.x, 32); a2.y += __shfl_xor(a2.y, 32);

    float2 r0 = ln_relu_pair(a0, true);
    float2 r1 = ln_relu_pair(a1, true);
    float2 r2 = ln_relu_pair(a2, true);

    ushort2* rw = reinterpret_cast<ushort2*>(A1bf + (size_t)node * (3 * D));
    float* ob = out + (size_t)node * 384;
    if (h == 0) {
        rw[sl] = f2bf2(r0);                                    // w0
        reinterpret_cast<float2*>(ob + 64)[sl] = r0;           // out slot 1
    } else {
        rw[32 + sl] = f2bf2(r1);                               // w1
        rw[64 + sl] = f2bf2(r2);                               // w2
        float2 o4;
        o4.x = r0.x - 0.5f * (r1.x + r2.x);
        o4.y = r0.y - 0.5f * (r1.y + r2.y);
        reinterpret_cast<float2*>(ob + 256)[sl] = o4;          // out slot 4
    }
}

// layer-2 gather + LN/ReLU + remaining output slots.
__global__ void gather2_kernel(const __hip_bfloat16* __restrict__ hnbf,
                               const __hip_bfloat16* __restrict__ A1bf,
                               const int* __restrict__ cnt, const int* __restrict__ packed,
                               const int* __restrict__ age, float* __restrict__ out) {
    int gid  = blockIdx.x * blockDim.x + threadIdx.x;
    int node = gid >> 6;
    int lane = gid & 63;
    if (node >= NN) return;
    int sl = lane & 31;
    int h  = lane >> 5;
    int n  = min(cnt[node], CAP);
    int nc4 = (n + 3) >> 2;
    int mc  = max(nc4 - 1, 0);
    const int* pl = packed + (size_t)node * CAP;
    float2 a0 = {0.f, 0.f}, a1 = {0.f, 0.f}, a2 = {0.f, 0.f};

    {
        int c0 = min(h, mc), c1 = min(h + 2, mc);
        int4 pa = *reinterpret_cast<const int4*>(pl + 4 * c0);
        int4 pb = *reinterpret_cast<const int4*>(pl + 4 * c1);
        int pA[4] = {pa.x, pa.y, pa.z, pa.w};
        int pB[4] = {pb.x, pb.y, pb.z, pb.w};
        #pragma unroll
        for (int k = 0; k < 8; ++k) {
            int i  = (k < 4) ? (4 * h + k) : (4 * (h + 2) + (k - 4));
            int pk = (k < 4) ? pA[k] : pB[k - 4];
            int idx = (i < n) ? (pk & 0x1FFFF) : ZROW;
            const ushort2* row = reinterpret_cast<const ushort2*>(
                A1bf + (size_t)idx * (3 * D));
            float2 v0 = bf22f2(row[sl]);        // w0
            float2 v1 = bf22f2(row[32 + sl]);   // w1 (+128B)
            float2 v2 = bf22f2(row[64 + sl]);   // w2 (+256B)
            a0.x += v0.x; a0.y += v0.y;
            a1.x += v1.x; a1.y += v1.y;
            a2.x += v2.x; a2.y += v2.y;
        }
    }
    for (int c = 4 + h; c < nc4; c += 2) {
        int4 pc = *reinterpret_cast<const int4*>(pl + 4 * c);
        int pC[4] = {pc.x, pc.y, pc.z, pc.w};
        #pragma unroll
        for (int k = 0; k < 4; ++k) {
            int i = 4 * c + k;
            int idx = (i < n) ? (pC[k] & 0x1FFFF) : ZROW;
            const ushort2* row = reinterpret_cast<const ushort2*>(
                A1bf + (size_t)idx * (3 * D));
            float2 v0 = bf22f2(row[sl]);
            float2 v1 = bf22f2(row[32 + sl]);
            float2 v2 = bf22f2(row[64 + sl]);
            a0.x += v0.x; a0.y += v0.y;
            a1.x += v1.x; a1.y += v1.y;
            a2.x += v2.x; a2.y += v2.y;
        }
    }
    a0.x += __shfl_xor(a0.x, 32); a0.y += __shfl_xor(a0.y, 32);
    a1.x += __shfl_xor(a1.x, 32); a1.y += __shfl_xor(a1.y, 32);
    a2.x += __shfl_xor(a2.x, 32); a2.y += __shfl_xor(a2.y, 32);

    float2 h20 = ln_relu_pair(a0, true);
    float2 h21 = ln_relu_pair(a1, true);
    float2 h22 = ln_relu_pair(a2, true);

    float2 hnv = bf22f2(reinterpret_cast<const ushort2*>(
        hnbf + (size_t)node * D)[sl]);
    int ag = age[node];
    float f = 1.f - 0.5f * (float)((ag >= 1) + (ag >= 2));
    float* ob = out + (size_t)node * 384;
    if (h == 0) {
        reinterpret_cast<float2*>(ob)[sl] = hnv;               // slot 0
        reinterpret_cast<float2*>(ob + 128)[sl] = h20;         // slot 2
    } else {
        float2 o3, o5;
        o3.x = hnv.x * f;
        o3.y = hnv.y * f;
        o5.x = h20.x - 0.5f * (h21.x + h22.x);
        o5.y = h20.y - 0.5f * (h21.y + h22.y);
        reinterpret_cast<float2*>(ob + 192)[sl] = o3;          // slot 3
        reinterpret_cast<float2*>(ob + 320)[sl] = o5;          // slot 5
    }
}

extern "C" void kernel_launch(void* const* d_in, const int* in_sizes, int n_in,
                              void* d_out, int out_size, void* d_ws, size_t ws_size,
                              hipStream_t stream) {
    const float* feature = (const float*)d_in[0];
    const int*   age     = (const int*)d_in[1];
    const int*   src     = (const int*)d_in[2];
    const int*   dst     = (const int*)d_in[3];
    float* out = (float*)d_out;

    size_t nd1 = (size_t)(NN + 1) * D;               // hnbf rows incl. zero row
    __hip_bfloat16* hnbf = (__hip_bfloat16*)d_ws;    // [NN+1][D]      ~12.8 MB
    __hip_bfloat16* A1bf = hnbf + nd1;               // [NN+1][3][D]   ~38.4 MB
    int* cnt    = (int*)(A1bf + (size_t)(NN + 1) * 3 * D);   // NN      0.4 MB
    int* packed = cnt + NN;                          // NN*CAP          25.6 MB
    unsigned* agePk = (unsigned*)(packed + (size_t)NN * CAP);   // 25 KB

    // ln also zeroes cnt/ZROW rows and builds agePk; must precede fillx/gathers.
    ln_kernel<<<(int)(((size_t)NN * D + 255) / 256), 256, 0, stream>>>(
        feature, age, hnbf, A1bf, cnt, agePk, NN);
    fillx_kernel<<<FILL_BLOCKS, 256, 0, stream>>>(src, dst, agePk, cnt, packed);
    gather1_kernel<<<(NN * 64 + 255) / 256, 256, 0, stream>>>(hnbf, cnt, packed, A1bf, out);
    gather2_kernel<<<(NN * 64 + 255) / 256, 256, 0, stream>>>(hnbf, A1bf, cnt, packed,
                                                              age, out);
}